// Round 14
// baseline (539.350 us; speedup 1.0000x reference)
//
#include <hip/hip_runtime.h>

// ---------------------------------------------------------------------------
// AtomExposureGNN: 3-layer GCN (N=50000, E=800000, DIN=64, H=128) + MLP head
// R12: A-operand bf16x2 split HOISTED out of the MFMA GEMM (was ~512 VALU
//      cyc/wave in-loop, serializing with MFMA). Producers now emit splits:
//      xsplit pre-pass for x; input-GEMM epilogue writes h0 as bf16 hi/lo
//      (no fp32 copy needed); agg epilogue emits hi/lo for layers 0,1.
//      GEMM hot loop = pure MFMA + loads. Same split values => same numerics.
// R9:  MFMA bf16x2-split GEMMs (ah*bh+ah*bl+al*bh), W pre-split/transposed.
// R5:  agg 8 loads in flight; fused MLP head.  R3: float4 gather, norm fold.
// ---------------------------------------------------------------------------

typedef unsigned short ushort_t;
typedef __attribute__((ext_vector_type(8))) short bf16x8;
typedef __attribute__((ext_vector_type(4))) float f32x4;

__device__ __forceinline__ void fma4(float4& acc, float s, const float4& v) {
    acc.x = fmaf(s, v.x, acc.x);
    acc.y = fmaf(s, v.y, acc.y);
    acc.z = fmaf(s, v.z, acc.z);
    acc.w = fmaf(s, v.w, acc.w);
}
__device__ __forceinline__ void add4(float4& acc, const float4& v) {
    acc.x += v.x; acc.y += v.y; acc.z += v.z; acc.w += v.w;
}

// bf16 round-to-nearest-even from fp32, and back
__device__ __forceinline__ ushort_t f2bf(float x) {
    union { float f; unsigned u; } v; v.f = x;
    unsigned r = v.u + 0x7FFFu + ((v.u >> 16) & 1u);
    return (ushort_t)(r >> 16);
}
__device__ __forceinline__ float bf2f(ushort_t h) {
    union { unsigned u; float f; } v; v.u = ((unsigned)h) << 16;
    return v.f;
}

constexpr int DIN_C = 64;
constexpr int H_C = 128;

// ---------------- CSR construction ----------------

__global__ __launch_bounds__(256) void count_deg_kernel(const int* __restrict__ dst,
                                                        int* __restrict__ cnt, int e) {
    int i = blockIdx.x * 256 + threadIdx.x;
    if (i < e) atomicAdd(&cnt[dst[i]], 1);
}

__global__ __launch_bounds__(512) void scan_blocks_kernel(const int* __restrict__ cnt,
                                                          int* __restrict__ excl,
                                                          int* __restrict__ bsums, int n) {
    __shared__ int s[2][512];
    int t = threadIdx.x;
    int i = blockIdx.x * 512 + t;
    int v = (i < n) ? cnt[i] : 0;
    s[0][t] = v;
    __syncthreads();
    int cur = 0;
    for (int off = 1; off < 512; off <<= 1) {
        int x = s[cur][t];
        if (t >= off) x += s[cur][t - off];
        s[cur ^ 1][t] = x;
        cur ^= 1;
        __syncthreads();
    }
    if (i < n) excl[i] = s[cur][t] - v;
    if (t == 511) bsums[blockIdx.x] = s[cur][t];
}

__global__ __launch_bounds__(128) void scan_tops_kernel(const int* __restrict__ bsums,
                                                        int* __restrict__ btops, int nb) {
    __shared__ int s[2][128];
    int t = threadIdx.x;
    int v = (t < nb) ? bsums[t] : 0;
    s[0][t] = v;
    __syncthreads();
    int cur = 0;
    for (int off = 1; off < 128; off <<= 1) {
        int x = s[cur][t];
        if (t >= off) x += s[cur][t - off];
        s[cur ^ 1][t] = x;
        cur ^= 1;
        __syncthreads();
    }
    if (t < nb) btops[t] = s[cur][t] - v;
}

__global__ __launch_bounds__(512) void finalize_nodes_kernel(
        const int* __restrict__ excl, const int* __restrict__ btops,
        const int* __restrict__ cnt, int* __restrict__ row_ptr,
        int* __restrict__ cursor, float* __restrict__ dis, int n, int e) {
    int i = blockIdx.x * 512 + threadIdx.x;
    if (i < n) {
        int rp = excl[i] + btops[blockIdx.x];
        row_ptr[i] = rp;
        cursor[i]  = rp;
        dis[i] = rsqrtf((float)(cnt[i] + 1));  // deg = indegree + self loop
    }
    if (i == 0) row_ptr[n] = e;
}

__global__ __launch_bounds__(256) void fill_csr_kernel(
        const int* __restrict__ src, const int* __restrict__ dst,
        int* __restrict__ cursor, int* __restrict__ csr_src, int e) {
    int i = blockIdx.x * 256 + threadIdx.x;
    if (i < e) {
        int s = src[i], d = dst[i];
        int pos = atomicAdd(&cursor[d], 1);
        csr_src[pos] = s;
    }
}

// ---------------- x split: fp32 -> bf16 hi/lo (elementwise) ----------------

__global__ __launch_bounds__(256) void xsplit_kernel(
        const float* __restrict__ x, ushort_t* __restrict__ xh,
        ushort_t* __restrict__ xl, int n) {
    int i = blockIdx.x * 256 + threadIdx.x;
    if (i < n) {
        float v = x[i];
        ushort_t h = f2bf(v);
        xh[i] = h;
        xl[i] = f2bf(v - bf2f(h));
    }
}

// ---------------- W split+transpose: fp32 W[k][n] -> bf16 WT_hi/lo[n][k] ----

__global__ __launch_bounds__(256) void wsplit_kernel(
        const float* __restrict__ Wc, const float* __restrict__ W_in,
        ushort_t* __restrict__ lt_hi, ushort_t* __restrict__ lt_lo,   // [3][128][128]
        ushort_t* __restrict__ it_hi, ushort_t* __restrict__ it_lo) { // [128][64]
    int i = blockIdx.x * 256 + threadIdx.x;
    if (i < 3 * 128 * 128) {
        int m = i >> 14, rem = i & 16383;
        int k = rem >> 7, n = rem & 127;
        float v = Wc[i];
        ushort_t h = f2bf(v);
        ushort_t l = f2bf(v - bf2f(h));
        lt_hi[(m << 14) + n * 128 + k] = h;
        lt_lo[(m << 14) + n * 128 + k] = l;
    } else {
        int j = i - 3 * 128 * 128;
        if (j < 64 * 128) {
            int k = j >> 7, n = j & 127;
            float v = W_in[j];
            ushort_t h = f2bf(v);
            ushort_t l = f2bf(v - bf2f(h));
            it_hi[n * 64 + k] = h;
            it_lo[n * 64 + k] = l;
        }
    }
}

// ---------------- MFMA GEMM (pre-split A): C = act(A @ W + bias) * rs[row] --
// A given as bf16 hi/lo [M][K]; hot loop is pure MFMA + 16B loads.
// acc += ah*bh + ah*bl + al*bh (al*bl ~2^-16, dropped).
// Wave = 16 rows x 128 cols; A frag: lane l -> row l&15, k = kb*32+(l>>4)*8+j.
// C/D: row = (l>>4)*4 + reg, col = l&15 (HW-verified mapping).
// WF32: write fp32 C. WSPLIT: write bf16 hi/lo split of the activated output.

template <int KSTEPS, bool RELU, bool BIAS, bool SCALE, bool WF32, bool WSPLIT>
__global__ __launch_bounds__(256) void gemm_mfma_kernel(
        const ushort_t* __restrict__ a_hi, const ushort_t* __restrict__ a_lo,
        const ushort_t* __restrict__ wt_hi, const ushort_t* __restrict__ wt_lo,
        const float* __restrict__ bias, const float* __restrict__ rs,
        float* __restrict__ C, ushort_t* __restrict__ c_hi,
        ushort_t* __restrict__ c_lo, int M) {
    constexpr int K = KSTEPS * 32;
    const int tid  = threadIdx.x;
    const int wid  = tid >> 6;
    const int lane = tid & 63;
    const int lo16 = lane & 15;
    const int hi4  = lane >> 4;            // 0..3
    const int r0   = blockIdx.x * 64 + wid * 16;

    f32x4 acc[8];
#pragma unroll
    for (int nt = 0; nt < 8; ++nt) {
        float b = BIAS ? bias[nt * 16 + lo16] : 0.f;
        acc[nt] = (f32x4){b, b, b, b};
    }

    int ar = r0 + lo16;                    // A-load row (clamped for tail)
    if (ar > M - 1) ar = M - 1;
    const ushort_t* Ah = a_hi + (size_t)ar * K;
    const ushort_t* Al = a_lo + (size_t)ar * K;

#pragma unroll
    for (int kb = 0; kb < KSTEPS; ++kb) {
        const int kof = kb * 32 + hi4 * 8;
        bf16x8 afh = *(const bf16x8*)(Ah + kof);
        bf16x8 afl = *(const bf16x8*)(Al + kof);
#pragma unroll
        for (int nt = 0; nt < 8; ++nt) {
            const size_t boff = (size_t)(nt * 16 + lo16) * K + kof;
            bf16x8 bfh = *(const bf16x8*)(wt_hi + boff);
            bf16x8 bfl = *(const bf16x8*)(wt_lo + boff);
            acc[nt] = __builtin_amdgcn_mfma_f32_16x16x32_bf16(afh, bfh, acc[nt], 0, 0, 0);
            acc[nt] = __builtin_amdgcn_mfma_f32_16x16x32_bf16(afh, bfl, acc[nt], 0, 0, 0);
            acc[nt] = __builtin_amdgcn_mfma_f32_16x16x32_bf16(afl, bfh, acc[nt], 0, 0, 0);
        }
    }

#pragma unroll
    for (int reg = 0; reg < 4; ++reg) {
        int r = r0 + hi4 * 4 + reg;
        if (r < M) {
            float s = SCALE ? rs[r] : 1.f;
#pragma unroll
            for (int nt = 0; nt < 8; ++nt) {
                float v = acc[nt][reg];
                if (RELU) v = fmaxf(v, 0.f);
                if (SCALE) v *= s;
                if (WF32) C[(size_t)r * 128 + nt * 16 + lo16] = v;
                if (WSPLIT) {
                    ushort_t h = f2bf(v);
                    c_hi[(size_t)r * 128 + nt * 16 + lo16] = h;
                    c_lo[(size_t)r * 128 + nt * 16 + lo16] = f2bf(v - bf2f(h));
                }
            }
        }
    }
}

// ---------------- Fused MLP head: out = relu(h @ W1 + b1) @ W2 + b2 ----------

__global__ __launch_bounds__(256) void head_kernel(
        const float* __restrict__ A, const float* __restrict__ W1,
        const float* __restrict__ b1, const float* __restrict__ W2,
        const float* __restrict__ b2, float* __restrict__ out, int M) {
    constexpr int K = 128, NC = 64;
    constexpr int CG  = NC / 4;
    constexpr int RPB = (256 / CG) * 8;  // 128 rows per block
    const int t  = threadIdx.x;
    const int tx = t % CG;
    const int ty = t / CG;
    const int c  = tx * 4;
    const int r0 = blockIdx.x * RPB + ty * 8;

    float4 bv = *(const float4*)&b1[c];
    float4 w2v = *(const float4*)&W2[c];
    float b2v = b2[0];

    float part[8];
    if (r0 + 8 <= M) {
        float4 acc[8];
#pragma unroll
        for (int i = 0; i < 8; ++i) acc[i] = bv;
        const float* Ar = A + (size_t)r0 * K;
#pragma unroll 4
        for (int k0 = 0; k0 < K; k0 += 4) {
            float4 w0 = *(const float4*)&W1[(size_t)(k0 + 0) * NC + c];
            float4 w1 = *(const float4*)&W1[(size_t)(k0 + 1) * NC + c];
            float4 w2 = *(const float4*)&W1[(size_t)(k0 + 2) * NC + c];
            float4 w3 = *(const float4*)&W1[(size_t)(k0 + 3) * NC + c];
#pragma unroll
            for (int i = 0; i < 8; ++i) {
                float4 a = *(const float4*)&Ar[(size_t)i * K + k0];
                fma4(acc[i], a.x, w0);
                fma4(acc[i], a.y, w1);
                fma4(acc[i], a.z, w2);
                fma4(acc[i], a.w, w3);
            }
        }
#pragma unroll
        for (int i = 0; i < 8; ++i) {
            float4 v = acc[i];
            v.x = fmaxf(v.x, 0.f); v.y = fmaxf(v.y, 0.f);
            v.z = fmaxf(v.z, 0.f); v.w = fmaxf(v.w, 0.f);
            part[i] = v.x * w2v.x + v.y * w2v.y + v.z * w2v.z + v.w * w2v.w;
        }
    } else {
#pragma unroll
        for (int i = 0; i < 8; ++i) {
            int r = r0 + i;
            part[i] = 0.f;
            if (r < M) {
                float4 acc = bv;
                const float* Ar = A + (size_t)r * K;
                for (int k0 = 0; k0 < K; k0 += 4) {
                    float4 a  = *(const float4*)&Ar[k0];
                    float4 w0 = *(const float4*)&W1[(size_t)(k0 + 0) * NC + c];
                    float4 w1 = *(const float4*)&W1[(size_t)(k0 + 1) * NC + c];
                    float4 w2 = *(const float4*)&W1[(size_t)(k0 + 2) * NC + c];
                    float4 w3 = *(const float4*)&W1[(size_t)(k0 + 3) * NC + c];
                    fma4(acc, a.x, w0);
                    fma4(acc, a.y, w1);
                    fma4(acc, a.z, w2);
                    fma4(acc, a.w, w3);
                }
                acc.x = fmaxf(acc.x, 0.f); acc.y = fmaxf(acc.y, 0.f);
                acc.z = fmaxf(acc.z, 0.f); acc.w = fmaxf(acc.w, 0.f);
                part[i] = acc.x * w2v.x + acc.y * w2v.y + acc.z * w2v.z + acc.w * w2v.w;
            }
        }
    }
#pragma unroll
    for (int i = 0; i < 8; ++i) {
        float v = part[i];
        v += __shfl_xor(v, 1);
        v += __shfl_xor(v, 2);
        v += __shfl_xor(v, 4);
        v += __shfl_xor(v, 8);
        part[i] = v;
    }
    if (tx == 0) {
#pragma unroll
        for (int i = 0; i < 8; ++i) {
            int r = r0 + i;
            if (r < M) out[r] = part[i] + b2v;
        }
    }
}

// ---------------- Aggregation + bias + BN + ReLU + residual ------------------
// One wave per node; float4 lanes; 2 half-waves, 4x unroll -> 8 gathers in
// flight. hwp pre-scaled by dis[src]; epilogue multiplies by dis[dst].
// If oh/ol non-null, also emits bf16 hi/lo split of the output (next GEMM's A).

__global__ __launch_bounds__(256) void agg_bn_kernel(
        const float* __restrict__ hwp, const int* __restrict__ row_ptr,
        const int* __restrict__ csr_src, const float* __restrict__ dis,
        const float* __restrict__ bc, const float* __restrict__ gamma_,
        const float* __restrict__ beta_, const float* __restrict__ rmean,
        const float* __restrict__ rvar,
        const float* __restrict__ h_in, float* __restrict__ h_out,
        ushort_t* __restrict__ oh, ushort_t* __restrict__ ol,
        int n, int residual) {
    int wid  = (blockIdx.x * 256 + threadIdx.x) >> 6;
    int lane = threadIdx.x & 63;
    if (wid >= n) return;
    const int half = lane >> 5;
    const int f    = (lane & 31) * 4;

    float4 a0 = {0.f, 0.f, 0.f, 0.f};
    float4 a1 = {0.f, 0.f, 0.f, 0.f};
    float4 a2 = {0.f, 0.f, 0.f, 0.f};
    float4 a3 = {0.f, 0.f, 0.f, 0.f};
    if (half == 0) a0 = *(const float4*)(hwp + (size_t)wid * H_C + f);

    const int beg = row_ptr[wid], end = row_ptr[wid + 1];
    int e = beg + half;
    for (; e + 6 < end; e += 8) {
        int s0 = csr_src[e];
        int s1 = csr_src[e + 2];
        int s2 = csr_src[e + 4];
        int s3 = csr_src[e + 6];
        float4 r0 = *(const float4*)(hwp + (size_t)s0 * H_C + f);
        float4 r1 = *(const float4*)(hwp + (size_t)s1 * H_C + f);
        float4 r2 = *(const float4*)(hwp + (size_t)s2 * H_C + f);
        float4 r3 = *(const float4*)(hwp + (size_t)s3 * H_C + f);
        add4(a0, r0);
        add4(a1, r1);
        add4(a2, r2);
        add4(a3, r3);
    }
    for (; e + 2 < end; e += 4) {
        int s0 = csr_src[e];
        int s1 = csr_src[e + 2];
        float4 r0 = *(const float4*)(hwp + (size_t)s0 * H_C + f);
        float4 r1 = *(const float4*)(hwp + (size_t)s1 * H_C + f);
        add4(a0, r0);
        add4(a1, r1);
    }
    if (e < end) {
        int s = csr_src[e];
        float4 r = *(const float4*)(hwp + (size_t)s * H_C + f);
        add4(a0, r);
    }
    add4(a0, a2);
    add4(a1, a3);
    add4(a0, a1);
    a0.x += __shfl_xor(a0.x, 32);
    a0.y += __shfl_xor(a0.y, 32);
    a0.z += __shfl_xor(a0.z, 32);
    a0.w += __shfl_xor(a0.w, 32);

    if (half == 0) {
        const float eps = 1e-5f;
        float dd = dis[wid];
        float4 b4 = *(const float4*)&bc[f];
        float4 g4 = *(const float4*)&gamma_[f];
        float4 be4 = *(const float4*)&beta_[f];
        float4 m4 = *(const float4*)&rmean[f];
        float4 v4 = *(const float4*)&rvar[f];
        float4 o;
        o.x = fmaf((fmaf(dd, a0.x, b4.x) - m4.x) * rsqrtf(v4.x + eps), g4.x, be4.x);
        o.y = fmaf((fmaf(dd, a0.y, b4.y) - m4.y) * rsqrtf(v4.y + eps), g4.y, be4.y);
        o.z = fmaf((fmaf(dd, a0.z, b4.z) - m4.z) * rsqrtf(v4.z + eps), g4.z, be4.z);
        o.w = fmaf((fmaf(dd, a0.w, b4.w) - m4.w) * rsqrtf(v4.w + eps), g4.w, be4.w);
        o.x = fmaxf(o.x, 0.f); o.y = fmaxf(o.y, 0.f);
        o.z = fmaxf(o.z, 0.f); o.w = fmaxf(o.w, 0.f);
        if (residual) {
            float4 r = *(const float4*)(h_in + (size_t)wid * H_C + f);
            add4(o, r);
        }
        *(float4*)(h_out + (size_t)wid * H_C + f) = o;
        if (oh) {
            ushort_t h0 = f2bf(o.x), h1 = f2bf(o.y), h2 = f2bf(o.z), h3 = f2bf(o.w);
            ushort_t l0 = f2bf(o.x - bf2f(h0));
            ushort_t l1 = f2bf(o.y - bf2f(h1));
            ushort_t l2 = f2bf(o.z - bf2f(h2));
            ushort_t l3 = f2bf(o.w - bf2f(h3));
            uint2 ph, pl;
            ph.x = (unsigned)h0 | ((unsigned)h1 << 16);
            ph.y = (unsigned)h2 | ((unsigned)h3 << 16);
            pl.x = (unsigned)l0 | ((unsigned)l1 << 16);
            pl.y = (unsigned)l2 | ((unsigned)l3 << 16);
            *(uint2*)(oh + (size_t)wid * H_C + f) = ph;
            *(uint2*)(ol + (size_t)wid * H_C + f) = pl;
        }
    }
}

// ---------------------------------------------------------------------------

extern "C" void kernel_launch(void* const* d_in, const int* in_sizes, int n_in,
                              void* d_out, int out_size, void* d_ws, size_t ws_size,
                              hipStream_t stream) {
    const float* x      = (const float*)d_in[0];
    const int*   ei     = (const int*)  d_in[1];
    const float* W_in   = (const float*)d_in[2];
    const float* b_in   = (const float*)d_in[3];
    const float* Wc     = (const float*)d_in[4];
    const float* bc     = (const float*)d_in[5];
    const float* gamma_ = (const float*)d_in[6];
    const float* beta_  = (const float*)d_in[7];
    const float* rmean  = (const float*)d_in[8];
    const float* rvar   = (const float*)d_in[9];
    const float* W1     = (const float*)d_in[10];
    const float* b1     = (const float*)d_in[11];
    const float* W2     = (const float*)d_in[12];
    const float* b2     = (const float*)d_in[13];
    float* out = (float*)d_out;

    const int M = in_sizes[0] / DIN_C;   // 50000 nodes
    const int E = in_sizes[1] / 2;       // 800000 edges
    const int* src = ei;
    const int* dst = ei + E;

    // Workspace carve-up (256B aligned)
    size_t off = 0;
    auto alloc = [&](size_t bytes) {
        void* p = (char*)d_ws + off;
        off += (bytes + 255) & ~(size_t)255;
        return p;
    };
    int*      cnt      = (int*)     alloc((size_t)M * 4);
    int*      excl     = (int*)     alloc((size_t)M * 4);
    int*      bsums    = (int*)     alloc(512);
    int*      btops    = (int*)     alloc(512);
    int*      row_ptr  = (int*)     alloc((size_t)(M + 1) * 4);
    int*      cursor   = (int*)     alloc((size_t)M * 4);
    float*    dis      = (float*)   alloc((size_t)M * 4);
    int*      csr_src  = (int*)     alloc((size_t)E * 4);
    ushort_t* lt_hi    = (ushort_t*)alloc((size_t)3 * 128 * 128 * 2);
    ushort_t* lt_lo    = (ushort_t*)alloc((size_t)3 * 128 * 128 * 2);
    ushort_t* it_hi    = (ushort_t*)alloc((size_t)128 * 64 * 2);
    ushort_t* it_lo    = (ushort_t*)alloc((size_t)128 * 64 * 2);
    ushort_t* xs_hi    = (ushort_t*)alloc((size_t)M * DIN_C * 2);
    ushort_t* xs_lo    = (ushort_t*)alloc((size_t)M * DIN_C * 2);
    ushort_t* hs_hi    = (ushort_t*)alloc((size_t)M * H_C * 2);
    ushort_t* hs_lo    = (ushort_t*)alloc((size_t)M * H_C * 2);
    float*    hA       = (float*)   alloc((size_t)M * H_C * 4);
    float*    hB       = (float*)   alloc((size_t)M * H_C * 4);
    float*    hw       = (float*)   alloc((size_t)M * H_C * 4);

    const int NB = (M + 511) / 512;

    // ---- input splits (x and W) ----
    xsplit_kernel<<<(M * DIN_C + 255) / 256, 256, 0, stream>>>(x, xs_hi, xs_lo, M * DIN_C);
    {
        const int total = 3 * 128 * 128 + 64 * 128;
        wsplit_kernel<<<(total + 255) / 256, 256, 0, stream>>>(
            Wc, W_in, lt_hi, lt_lo, it_hi, it_lo);
    }

    // ---- CSR build ----
    hipMemsetAsync(cnt, 0, (size_t)M * 4, stream);
    count_deg_kernel<<<(E + 255) / 256, 256, 0, stream>>>(dst, cnt, E);
    scan_blocks_kernel<<<NB, 512, 0, stream>>>(cnt, excl, bsums, M);
    scan_tops_kernel<<<1, 128, 0, stream>>>(bsums, btops, NB);
    finalize_nodes_kernel<<<NB, 512, 0, stream>>>(excl, btops, cnt, row_ptr, cursor, dis, M, E);
    fill_csr_kernel<<<(E + 255) / 256, 256, 0, stream>>>(src, dst, cursor, csr_src, E);

    const int GEMM_GRID = (M + 63) / 64;

    // ---- h0 = relu(x @ W_in + b_in): split-only output (layer0 has no residual)
    gemm_mfma_kernel<2, true, true, false, false, true><<<GEMM_GRID, 256, 0, stream>>>(
        xs_hi, xs_lo, it_hi, it_lo, b_in, nullptr, nullptr, hs_hi, hs_lo, M);

    // ---- 3 GCN layers ----
    float* cur = hA;   // fp32 h of previous layer (residual input); hA dummy for layer0
    float* nxt = hB;
    for (int layer = 0; layer < 3; ++layer) {
        // hw' = (h @ Wc) * dis[row]; A from pre-split hs
        gemm_mfma_kernel<4, false, false, true, true, false><<<GEMM_GRID, 256, 0, stream>>>(
            hs_hi, hs_lo, lt_hi + (size_t)layer * 16384, lt_lo + (size_t)layer * 16384,
            nullptr, dis, hw, nullptr, nullptr, M);
        // agg writes fp32 h (nxt) and, for layers 0,1, bf16 split (next GEMM's A)
        agg_bn_kernel<<<(M * 64 + 255) / 256, 256, 0, stream>>>(
            hw, row_ptr, csr_src, dis,
            bc + (size_t)layer * H_C, gamma_ + (size_t)layer * H_C,
            beta_ + (size_t)layer * H_C, rmean + (size_t)layer * H_C,
            rvar + (size_t)layer * H_C,
            cur, nxt,
            layer < 2 ? hs_hi : nullptr, layer < 2 ? hs_lo : nullptr,
            M, layer > 0 ? 1 : 0);
        float* tmp = cur; cur = nxt; nxt = tmp;
    }

    // ---- fused head: out = relu(h @ W1 + b1) @ W2 + b2 ----
    {
        constexpr int RPB = (256 / (64 / 4)) * 8;  // 128 rows/block
        head_kernel<<<(M + RPB - 1) / RPB, 256, 0, stream>>>(
            cur, W1, b1, W2, b2, out, M);
    }
}